// Round 19
// baseline (612.791 us; speedup 1.0000x reference)
//
#include <hip/hip_runtime.h>

typedef short short8 __attribute__((ext_vector_type(8)));
typedef float f32x4 __attribute__((ext_vector_type(4)));
typedef float f32x2 __attribute__((ext_vector_type(2)));
typedef _Float16 h2 __attribute__((ext_vector_type(2)));

#if __has_builtin(__builtin_amdgcn_cvt_pk_fp8_f32) && __has_builtin(__builtin_amdgcn_cvt_pk_f32_fp8)
#define HAVE_FP8 1
#else
#define HAVE_FP8 0
#endif

__device__ __forceinline__ unsigned short f2bf(float f) {
  union { float f; unsigned u; } a; a.f = f;
  unsigned r = a.u + 0x7fffu + ((a.u >> 16) & 1u);
  return (unsigned short)(r >> 16);
}

__device__ __forceinline__ h2 u2h2(unsigned w) {
  union { unsigned u; h2 h; } q; q.u = w; return q.h;
}

__device__ __forceinline__ unsigned short f2h(float f) {
  union { _Float16 h; unsigned short s; } q; q.h = (_Float16)f; return q.s;
}

// ---------------- tap offset table: off[k] = ci*3136 + ky*56 + kx ----------------
__global__ void offtab_k(unsigned* __restrict__ off_tab) {
  const int k = blockIdx.x * 256 + threadIdx.x;  // 81*256 = 20736 exact
  const int ci = k / 81, rr = k % 81;
  const int ky = rr / 9, kx = rr % 9;
  off_tab[k] = (unsigned)(ci * 3136 + ky * 56 + kx);
}

// ---------------- prim_w fp32 -> bf16 tiled [kb][co][8] ----------------
__global__ __launch_bounds__(256) void wconv_k(const float* __restrict__ pw,
                                               unsigned short* __restrict__ wbf) {
  const int kb = blockIdx.x, co = threadIdx.x;  // 2592 blocks
  const float4* src = (const float4*)(pw + (long)co * 20736 + kb * 8);
  const float4 a = src[0], b = src[1];
  union { unsigned short s[8]; short8 v; } o;
  o.s[0] = f2bf(a.x); o.s[1] = f2bf(a.y); o.s[2] = f2bf(a.z); o.s[3] = f2bf(a.w);
  o.s[4] = f2bf(b.x); o.s[5] = f2bf(b.y); o.s[6] = f2bf(b.z); o.s[7] = f2bf(b.w);
  *reinterpret_cast<short8*>(&wbf[((long)kb * 256 + co) * 8]) = o.v;
}

// ---------------- conv1: [8,3,64,64] -> bf16 h [8,256,56,56], relu ----------------
__global__ __launch_bounds__(256) void conv1_k(const float* __restrict__ x,
                                               const float* __restrict__ w,
                                               const float* __restrict__ bias,
                                               unsigned short* __restrict__ h_bf) {
  __shared__ float xl[12288];
  __shared__ float wl[244];
  const int blk = blockIdx.x;          // 2048 = 8b * 256co
  const int b = blk >> 8, co = blk & 255;
  const int t = threadIdx.x;
  const float4* xb = (const float4*)(x + b * 12288);
  float4* xl4 = (float4*)xl;
  for (int r = t; r < 3072; r += 256) xl4[r] = xb[r];
  for (int r = t; r < 243; r += 256) wl[r] = w[co * 243 + r];
  __syncthreads();
  if (t >= 224) return;
  const int ox = t % 56, oy0 = (t / 56) * 14;
  float acc[14];
#pragma unroll
  for (int j = 0; j < 14; ++j) acc[j] = 0.f;
  for (int ci = 0; ci < 3; ++ci)
    for (int kx = 0; kx < 9; ++kx) {
      const int base = ci * 4096 + oy0 * 64 + ox + kx;
      float win[22];
#pragma unroll
      for (int q = 0; q < 22; ++q) win[q] = xl[base + q * 64];
#pragma unroll
      for (int ky = 0; ky < 9; ++ky) {
        const float wv = wl[ci * 81 + ky * 9 + kx];
#pragma unroll
        for (int j = 0; j < 14; ++j) acc[j] = fmaf(wv, win[j + ky], acc[j]);
      }
    }
  const float bv = bias[co];
  unsigned short* hp = h_bf + (((long)b * 256 + co) * 56 + oy0) * 56 + ox;
#pragma unroll
  for (int j = 0; j < 14; ++j) {
    float v = acc[j] + bv;
    v = v > 0.f ? v : 0.f;
    hp[j * 56] = f2bf(v);
  }
}

// ---------------- prim conv implicit GEMM v12: dbuf LDS + 8-way K-split ----------------
// C[m=4608][co=256], K=20736. grid (72 mtile, 8 ksplit) = 576 blocks (2.25/CU),
// 512 thr = 8 waves (2M x 4N). 81 k-steps of 32 per block, ONE barrier per step,
// load->use distance 2 iterations. Staging regs = proven set (pa + pb0..3).
__global__ __launch_bounds__(512) void prim_gemm(const unsigned short* __restrict__ h_bf,
                                                 const uint4* __restrict__ wbf4,
                                                 const unsigned* __restrict__ off_tab,
                                                 float* __restrict__ C_part) {
  __shared__ uint4 A4[2][256];    // [buf][c:4][row:64]
  __shared__ uint4 B4[2][1024];   // [buf][c:4][co:256]
  const int t = threadIdx.x;
  const int lane = t & 63, w = t >> 6;
  const int mt = blockIdx.x, kz = blockIdx.y;
  const int k0 = kz * 2592;  // 81 k-steps of 32
  const bool isA = (t < 256);
  const int ar = t & 63, ac = (t >> 6) & 3;
  const int m = mt * 64 + ar;
  const int b = m / 576, yx = m % 576;
  const int oy = yx / 24, ox = yx % 24;
  const long base_p = (long)b * 802816 + oy * 112 + ox * 2;
  const int bco = t & 255;
  const int wm = w >> 2, wn = w & 3;
  const int fr = lane & 15, fg = lane >> 4;
  f32x4 acc[2][4];
#pragma unroll
  for (int i2 = 0; i2 < 2; ++i2)
#pragma unroll
    for (int j = 0; j < 4; ++j)
#pragma unroll
      for (int e = 0; e < 4; ++e) acc[i2][j][e] = 0.f;

  union { unsigned short s[8]; uint4 v; } pa;
  uint4 pb0, pb1, pb2, pb3;
  auto loadA = [&](int kt) {
    const int kb = k0 + kt * 32 + ac * 8;
#pragma unroll
    for (int j = 0; j < 8; ++j) pa.s[j] = h_bf[base_p + off_tab[kb + j]];
  };
  auto loadB = [&](int kt) {
    const int kb0 = (k0 + kt * 32) >> 3;
    pb0 = wbf4[(kb0 + 0) * 256 + bco];
    pb1 = wbf4[(kb0 + 1) * 256 + bco];
    pb2 = wbf4[(kb0 + 2) * 256 + bco];
    pb3 = wbf4[(kb0 + 3) * 256 + bco];
  };
  // prologue: tile 0 -> buf0; prefetch tile 1 into regs
  if (isA) loadA(0); else loadB(0);
  if (isA) {
    A4[0][ac * 64 + ar] = pa.v;
  } else {
    B4[0][bco] = pb0;
    B4[0][256 + bco] = pb1;
    B4[0][512 + bco] = pb2;
    B4[0][768 + bco] = pb3;
  }
  if (isA) loadA(1); else loadB(1);
  __syncthreads();

  for (int kt = 0; kt < 81; ++kt) {
    const int cur = kt & 1, nxt = cur ^ 1;
    if (kt < 80) {  // stage tile kt+1 (in regs) into the other buffer
      if (isA) {
        A4[nxt][ac * 64 + ar] = pa.v;
      } else {
        B4[nxt][bco] = pb0;
        B4[nxt][256 + bco] = pb1;
        B4[nxt][512 + bco] = pb2;
        B4[nxt][768 + bco] = pb3;
      }
      if (kt < 79) { if (isA) loadA(kt + 2); else loadB(kt + 2); }
    }
    const short8* A8 = (const short8*)A4[cur];
    const short8* B8 = (const short8*)B4[cur];
    const short8 a0 = A8[fg * 64 + wm * 32 + fr];
    const short8 a1 = A8[fg * 64 + wm * 32 + 16 + fr];
    const short8 b0 = B8[fg * 256 + wn * 64 + fr];
    const short8 b1 = B8[fg * 256 + wn * 64 + 16 + fr];
    const short8 b2 = B8[fg * 256 + wn * 64 + 32 + fr];
    const short8 b3 = B8[fg * 256 + wn * 64 + 48 + fr];
    acc[0][0] = __builtin_amdgcn_mfma_f32_16x16x32_bf16(a0, b0, acc[0][0], 0, 0, 0);
    acc[0][1] = __builtin_amdgcn_mfma_f32_16x16x32_bf16(a0, b1, acc[0][1], 0, 0, 0);
    acc[0][2] = __builtin_amdgcn_mfma_f32_16x16x32_bf16(a0, b2, acc[0][2], 0, 0, 0);
    acc[0][3] = __builtin_amdgcn_mfma_f32_16x16x32_bf16(a0, b3, acc[0][3], 0, 0, 0);
    acc[1][0] = __builtin_amdgcn_mfma_f32_16x16x32_bf16(a1, b0, acc[1][0], 0, 0, 0);
    acc[1][1] = __builtin_amdgcn_mfma_f32_16x16x32_bf16(a1, b1, acc[1][1], 0, 0, 0);
    acc[1][2] = __builtin_amdgcn_mfma_f32_16x16x32_bf16(a1, b2, acc[1][2], 0, 0, 0);
    acc[1][3] = __builtin_amdgcn_mfma_f32_16x16x32_bf16(a1, b3, acc[1][3], 0, 0, 0);
    __syncthreads();
  }
#pragma unroll
  for (int i2 = 0; i2 < 2; ++i2)
#pragma unroll
    for (int j = 0; j < 4; ++j)
#pragma unroll
      for (int e = 0; e < 4; ++e) {
        const int row = mt * 64 + wm * 32 + i2 * 16 + fg * 4 + e;
        const int col = wn * 64 + j * 16 + fr;
        C_part[((long)kz * 4608 + row) * 256 + col] = acc[i2][j][e];
      }
}

// ------- combine 8 K-split partials + bias + squash -> u fp32 [8,18432,8] -------
__global__ __launch_bounds__(256) void combine_k(const float* __restrict__ C_part,
                                                 const float* __restrict__ prim_b,
                                                 float* __restrict__ u) {
  const int cap = blockIdx.x * 256 + threadIdx.x;
  const int b = cap / 18432, r = cap % 18432;
  const int g = r / 576, yx = r % 576;
  const long m = (long)b * 576 + yx;
  float pv[8];
#pragma unroll
  for (int e = 0; e < 8; ++e) pv[e] = prim_b[g * 8 + e];
#pragma unroll
  for (int kz = 0; kz < 8; ++kz) {
    const float4* cp = (const float4*)(C_part + ((long)kz * 4608 + m) * 256 + g * 8);
    const float4 f0 = cp[0], f1 = cp[1];
    pv[0] += f0.x; pv[1] += f0.y; pv[2] += f0.z; pv[3] += f0.w;
    pv[4] += f1.x; pv[5] += f1.y; pv[6] += f1.z; pv[7] += f1.w;
  }
  float sn = 0.f;
#pragma unroll
  for (int e = 0; e < 8; ++e) sn += pv[e] * pv[e];
  const float f = sn / (1.f + sn) / (sqrtf(sn) + 1e-8f);
  float4 o0, o1;
  o0.x = pv[0] * f; o0.y = pv[1] * f; o0.z = pv[2] * f; o0.w = pv[3] * f;
  o1.x = pv[4] * f; o1.y = pv[5] * f; o1.z = pv[6] * f; o1.w = pv[7] * f;
  float4* up = (float4*)(u + (long)cap * 8);
  up[0] = o0; up[1] = o1;
}

// ---------------- fused pass1 + u_hat materialization ----------------
__global__ __launch_bounds__(512) void route1_fused(const float* __restrict__ W,
                                                    const float* __restrict__ u,
                                                    uint4* __restrict__ uhat4,
                                                    float* __restrict__ S1) {
  __shared__ float4 u_l[8][64];
  __shared__ float red[8][128];
#if HAVE_FP8
  __shared__ unsigned char ubuf[32][128];   // fp8 staging, 4 KB
#endif
  const int blk = blockIdx.x;
  const int t = threadIdx.x;
  const int n = blk / 576;
  const int i0 = (blk % 576) * 32;
  const long unit = (long)blk * 512 + t;
  {
    const int b = t >> 6, f = t & 63;
    u_l[b][f] = ((const float4*)(u + ((long)b * 18432 + i0) * 8))[f];
  }
  const float4* ws = (const float4*)(W + unit * 8);
  const float4 wa = ws[0], wb = ws[1];
  __syncthreads();
  const int il = t >> 4, d = t & 15;
  const int w = t >> 6, lane = t & 63;
  float uh[8];
#pragma unroll
  for (int b = 0; b < 8; ++b) {
    const float4 p0 = u_l[b][il * 2], p1 = u_l[b][il * 2 + 1];
    uh[b] = wa.x * p0.x + wa.y * p0.y + wa.z * p0.z + wa.w * p0.w +
            wb.x * p1.x + wb.y * p1.y + wb.z * p1.z + wb.w * p1.w;
  }
#if HAVE_FP8
#pragma unroll
  for (int b = 0; b < 8; ++b) {
    const int v8 = __builtin_amdgcn_cvt_pk_fp8_f32(uh[b] * 256.f, 0.f, 0, false);
    ubuf[il][b * 16 + d] = (unsigned char)(v8 & 0xff);
  }
#else
  unsigned short* up = (unsigned short*)uhat4 + ((long)n * 18432 + i0 + il) * 128 + d;
#pragma unroll
  for (int b = 0; b < 8; ++b) up[b * 16] = f2h(uh[b]);
#endif
#pragma unroll
  for (int b = 0; b < 8; ++b) {
    float v = uh[b];
    v += __shfl_xor(v, 16);   // reduce over i_local bits (lane bits 4,5)
    v += __shfl_xor(v, 32);
    if (lane < 16) red[w][b * 16 + lane] = v;
  }
  __syncthreads();
#if HAVE_FP8
  if (t < 256) {   // 32 rows x 128B = 256 uint4, coalesced
    const uint4* ub4 = (const uint4*)ubuf;
    uhat4[((long)n * 18432 + i0) * 8 + t] = ub4[t];
  }
#endif
  if (t < 128) {
    float s = 0.f;
#pragma unroll
    for (int w2 = 0; w2 < 8; ++w2) s += red[w2][t];
    S1[(long)blk * 128 + t] = s;
  }
}

__global__ __launch_bounds__(256) void route_reduce1(const float* __restrict__ S1,
                                                     float* __restrict__ vsum) {
  __shared__ float lds[256];
  const int bn = blockIdx.x;
  const int b = bn / 50, n = bn % 50;
  const int t = threadIdx.x;
  const int kk = t >> 4, dd = t & 15;
  float s = 0.f;
  const float* p = S1 + (long)n * 576 * 128 + b * 16 + dd;
  for (int j = kk; j < 576; j += 16) s += p[(long)j * 128];
  lds[t] = s;
  __syncthreads();
  for (int off = 128; off >= 16; off >>= 1) {
    if (t < off) lds[t] += lds[t + off];
    __syncthreads();
  }
  if (t < 16) {
    const float S = lds[t] * 0.02f;
    float sq = S * S;
    sq += __shfl_xor(sq, 1);
    sq += __shfl_xor(sq, 2);
    sq += __shfl_xor(sq, 4);
    sq += __shfl_xor(sq, 8);
    const float f = sq / (1.f + sq) / (sqrtf(sq) + 1e-8f);
    vsum[bn * 16 + t] += S * f;
  }
}

// ---------------- routing passes 2/3 from materialized u_hat ----------------
__global__ __launch_bounds__(256) void route_uhat(const uint4* __restrict__ uh4,
                                                  const float* __restrict__ vsum,
                                                  float* __restrict__ S_part) {
  const int t = threadIdx.x;
  const int w = t >> 6, lane = t & 63;
  const int b0 = 2 * w;
  const bool vn = lane < 50;
  const int nr = vn ? lane : 49;
  const int bi = blockIdx.x;
  const int i_base = bi * 16;

  float vs0[16], vs1[16], Sa0[16], Sa1[16];
#pragma unroll
  for (int d = 0; d < 16; ++d) {
    vs0[d] = vsum[(b0 * 50 + nr) * 16 + d];
    vs1[d] = vsum[((b0 + 1) * 50 + nr) * 16 + d];
    Sa0[d] = 0.f;
    Sa1[d] = 0.f;
  }

#if HAVE_FP8
  const float INV = 1.f / 256.f;
  auto base4 = [&](int i) -> long { return ((long)nr * 18432 + i) * 8 + b0; };
  uint4 c0, c1;
  { const long p = base4(i_base); c0 = uh4[p]; c1 = uh4[p + 1]; }
  for (int ii = 0; ii < 16; ++ii) {
    uint4 n0, n1;
    if (ii < 15) { const long p = base4(i_base + ii + 1); n0 = uh4[p]; n1 = uh4[p + 1]; }
    float uh0[16], uh1[16];
    {
      const unsigned* q0 = (const unsigned*)&c0;
      const unsigned* q1 = (const unsigned*)&c1;
#pragma unroll
      for (int qw = 0; qw < 4; ++qw) {
        const f32x2 lo0 = __builtin_amdgcn_cvt_pk_f32_fp8(q0[qw], false);
        const f32x2 hi0 = __builtin_amdgcn_cvt_pk_f32_fp8(q0[qw], true);
        uh0[qw * 4 + 0] = lo0[0]; uh0[qw * 4 + 1] = lo0[1];
        uh0[qw * 4 + 2] = hi0[0]; uh0[qw * 4 + 3] = hi0[1];
        const f32x2 lo1 = __builtin_amdgcn_cvt_pk_f32_fp8(q1[qw], false);
        const f32x2 hi1 = __builtin_amdgcn_cvt_pk_f32_fp8(q1[qw], true);
        uh1[qw * 4 + 0] = lo1[0]; uh1[qw * 4 + 1] = lo1[1];
        uh1[qw * 4 + 2] = hi1[0]; uh1[qw * 4 + 3] = hi1[1];
      }
    }
#else
  const float INV = 1.f;
  auto base4 = [&](int i) -> long { return ((long)nr * 18432 + i) * 16 + b0 * 2; };
  uint4 c0, c1, c2, c3;
  { const long p = base4(i_base); c0 = uh4[p]; c1 = uh4[p + 1]; c2 = uh4[p + 2]; c3 = uh4[p + 3]; }
  for (int ii = 0; ii < 16; ++ii) {
    uint4 n0, n1, n2, n3;
    if (ii < 15) {
      const long p = base4(i_base + ii + 1);
      n0 = uh4[p]; n1 = uh4[p + 1]; n2 = uh4[p + 2]; n3 = uh4[p + 3];
    }
    float uh0[16], uh1[16];
    {
      const unsigned* w0 = (const unsigned*)&c0;
      const unsigned* w1 = (const unsigned*)&c1;
      const unsigned* w2 = (const unsigned*)&c2;
      const unsigned* w3 = (const unsigned*)&c3;
#pragma unroll
      for (int q = 0; q < 4; ++q) {
        h2 hh = u2h2(w0[q]); uh0[q * 2] = (float)hh[0]; uh0[q * 2 + 1] = (float)hh[1];
        hh = u2h2(w1[q]); uh0[8 + q * 2] = (float)hh[0]; uh0[8 + q * 2 + 1] = (float)hh[1];
        hh = u2h2(w2[q]); uh1[q * 2] = (float)hh[0]; uh1[q * 2 + 1] = (float)hh[1];
        hh = u2h2(w3[q]); uh1[8 + q * 2] = (float)hh[0]; uh1[8 + q * 2 + 1] = (float)hh[1];
      }
    }
#endif
    float lg0 = 0.f, lg1 = 0.f;
#pragma unroll
    for (int d = 0; d < 16; ++d) {
      lg0 = fmaf(uh0[d], vs0[d], lg0);
      lg1 = fmaf(uh1[d], vs1[d], lg1);
    }
    float p0 = vn ? __expf(lg0 * INV) : 0.f;
    float p1 = vn ? __expf(lg1 * INV) : 0.f;
    float sm0 = p0, sm1 = p1;
    sm0 += __shfl_xor(sm0, 1);
    sm1 += __shfl_xor(sm1, 1);
    sm0 += __shfl_xor(sm0, 2);
    sm1 += __shfl_xor(sm1, 2);
    sm0 += __shfl_xor(sm0, 4);
    sm1 += __shfl_xor(sm1, 4);
    sm0 += __shfl_xor(sm0, 8);
    sm1 += __shfl_xor(sm1, 8);
    sm0 += __shfl_xor(sm0, 16);
    sm1 += __shfl_xor(sm1, 16);
    sm0 += __shfl_xor(sm0, 32);
    sm1 += __shfl_xor(sm1, 32);
    const float sc0 = p0 / sm0;
    const float sc1 = p1 / sm1;
#pragma unroll
    for (int d = 0; d < 16; ++d) {
      Sa0[d] = fmaf(sc0, uh0[d], Sa0[d]);
      Sa1[d] = fmaf(sc1, uh1[d], Sa1[d]);
    }
#if HAVE_FP8
    c0 = n0; c1 = n1;
#else
    c0 = n0; c1 = n1; c2 = n2; c3 = n3;
#endif
  }
  if (vn) {
    float* Sp0 = S_part + (long)bi * 6400 + b0 * 800 + lane * 16;
    float* Sp1 = Sp0 + 800;
#pragma unroll
    for (int d = 0; d < 16; ++d) {
      Sp0[d] = Sa0[d] * INV;
      Sp1[d] = Sa1[d] * INV;
    }
  }
}

// ---------------- routing pass (fp32 fallback, proven; 576 blocks) ----------------
__global__ __launch_bounds__(512, 4) void route_pass_f32(const float* __restrict__ W,
                                                         const float* __restrict__ u,
                                                         const float* __restrict__ vsum,
                                                         float* __restrict__ S_part) {
  const int t = threadIdx.x;
  const int b = t >> 6;
  const int lane = t & 63;
  const int d = lane & 15, nq = lane >> 4;
  const int qmax = (nq == 3) ? 11 : 13;
  int nn[13];
  float vs[13], Sa[13], uh[13], lg[13];
#pragma unroll
  for (int q = 0; q < 13; ++q) {
    const int n = nq * 13 + q;
    const bool valid = n < 50;
    nn[q] = valid ? n : 49;
    vs[q] = valid ? vsum[(b * 50 + n) * 16 + d] : 0.f;
    Sa[q] = 0.f;
  }
  const int bi = blockIdx.x;
  for (int ii = 0; ii < 32; ++ii) {
    const int i = bi * 32 + ii;
    const float4* up = (const float4*)(u + ((long)b * 18432 + i) * 8);
    const float4 u0 = up[0], u1 = up[1];
    const float* Wi = W + (long)i * 128 + d * 8;
#pragma unroll
    for (int q = 0; q < 13; ++q) {
      const float4* wp = (const float4*)(Wi + (long)nn[q] * 2359296);
      const float4 w0 = wp[0], w1 = wp[1];
      const float s = w0.x * u0.x + w0.y * u0.y + w0.z * u0.z + w0.w * u0.w +
                      w1.x * u1.x + w1.y * u1.y + w1.z * u1.z + w1.w * u1.w;
      uh[q] = s;
      float v = s * vs[q];
      v += __shfl_xor(v, 1);
      v += __shfl_xor(v, 2);
      v += __shfl_xor(v, 4);
      v += __shfl_xor(v, 8);
      lg[q] = (q < qmax) ? v : -1e30f;
    }
    float mx = lg[0];
#pragma unroll
    for (int q = 1; q < 13; ++q) mx = fmaxf(mx, lg[q]);
    mx = fmaxf(mx, __shfl_xor(mx, 16));
    mx = fmaxf(mx, __shfl_xor(mx, 32));
    float sm = 0.f;
#pragma unroll
    for (int q = 0; q < 13; ++q) {
      const float e = __expf(lg[q] - mx);
      lg[q] = e;
      sm += e;
    }
    sm += __shfl_xor(sm, 16);
    sm += __shfl_xor(sm, 32);
    const float inv = 1.f / sm;
#pragma unroll
    for (int q = 0; q < 13; ++q) Sa[q] = fmaf(lg[q] * inv, uh[q], Sa[q]);
  }
  float* Sp = S_part + ((long)bi * 8 + b) * 800;
#pragma unroll
  for (int q = 0; q < 13; ++q)
    if (q < qmax) Sp[(nq * 13 + q) * 16 + d] = Sa[q];
}

// ---------------- reduce nparts partials -> v = squash(S); vsum += v or v3 = v ------
__global__ __launch_bounds__(256) void route_reduce(const float* __restrict__ S_part,
                                                    float* __restrict__ vsum,
                                                    float* __restrict__ v3,
                                                    const int pass, const int nparts) {
  __shared__ float lds[256];
  const int bn = blockIdx.x;
  const int b = bn / 50, n = bn % 50;
  const int t = threadIdx.x;
  const int kk = t >> 4, dd = t & 15;
  float s = 0.f;
  const float* p = S_part + (long)b * 800 + n * 16 + dd;
  for (int j = kk; j < nparts; j += 16) s += p[(long)j * 6400];
  lds[t] = s;
  __syncthreads();
  for (int off = 128; off >= 16; off >>= 1) {
    if (t < off) lds[t] += lds[t + off];
    __syncthreads();
  }
  if (t < 16) {
    const float S = lds[t];
    float sq = S * S;
    sq += __shfl_xor(sq, 1);
    sq += __shfl_xor(sq, 2);
    sq += __shfl_xor(sq, 4);
    sq += __shfl_xor(sq, 8);
    const float f = sq / (1.f + sq) / (sqrtf(sq) + 1e-8f);
    const float v = S * f;
    const int o = bn * 16 + t;
    if (pass < 3) vsum[o] += v;
    else v3[o] = v;
  }
}

// ---------------- preds, argmax, select masked capsule ----------------
__global__ __launch_bounds__(512) void head_k(const float* __restrict__ v3,
                                              float* __restrict__ out,
                                              float* __restrict__ selv,
                                              int* __restrict__ idxs) {
  __shared__ float pl[400];
  const int t = threadIdx.x;
  if (t < 400) {
    const float4* vp = (const float4*)(v3 + t * 16);
    const float4 a = vp[0], b = vp[1], c = vp[2], d = vp[3];
    const float s = a.x * a.x + a.y * a.y + a.z * a.z + a.w * a.w +
                    b.x * b.x + b.y * b.y + b.z * b.z + b.w * b.w +
                    c.x * c.x + c.y * c.y + c.z * c.z + c.w * c.w +
                    d.x * d.x + d.y * d.y + d.z * d.z + d.w * d.w;
    const float p = sqrtf(s);
    out[t] = p;
    pl[t] = p;
  }
  __syncthreads();
  if (t < 8) {
    float best = -1e30f;
    int bi = 0;
    for (int n = 0; n < 50; ++n) {
      const float p = pl[t * 50 + n];
      if (p > best) { best = p; bi = n; }
    }
    idxs[t] = bi;
    for (int k = 0; k < 16; ++k) selv[t * 16 + k] = v3[(t * 50 + bi) * 16 + k];
  }
}

// ---------------- decoder ----------------
__global__ __launch_bounds__(512) void d1_k(const float* __restrict__ selv,
                                            const int* __restrict__ idxs,
                                            const float* __restrict__ d1w,
                                            const float* __restrict__ d1b,
                                            float* __restrict__ r1) {
  const int b = blockIdx.x, j = threadIdx.x;
  const int idx = idxs[b];
  const float* wr = d1w + j * 800 + idx * 16;
  float acc = d1b[j];
#pragma unroll
  for (int k = 0; k < 16; ++k) acc = fmaf(selv[b * 16 + k], wr[k], acc);
  r1[b * 512 + j] = acc > 0.f ? acc : 0.f;
}

__global__ __launch_bounds__(256) void d2_k(const float* __restrict__ r1,
                                            const float* __restrict__ d2w,
                                            const float* __restrict__ d2b,
                                            float* __restrict__ r2) {
  __shared__ float rl[512];
  const int b = blockIdx.y;
  const int j = blockIdx.x * 256 + threadIdx.x;
  for (int r = threadIdx.x; r < 512; r += 256) rl[r] = r1[b * 512 + r];
  __syncthreads();
  const float4* wr = (const float4*)(d2w + (long)j * 512);
  float acc = d2b[j];
  for (int k4 = 0; k4 < 128; ++k4) {
    const float4 w = wr[k4];
    acc += w.x * rl[k4 * 4] + w.y * rl[k4 * 4 + 1] + w.z * rl[k4 * 4 + 2] + w.w * rl[k4 * 4 + 3];
  }
  r2[b * 1024 + j] = acc > 0.f ? acc : 0.f;
}

__global__ __launch_bounds__(256) void d3_k(const float* __restrict__ r2,
                                            const float* __restrict__ d3w,
                                            const float* __restrict__ d3b,
                                            float* __restrict__ out) {
  __shared__ float rl[8192];
  const int j = blockIdx.x * 256 + threadIdx.x;
  float4* rl4 = (float4*)rl;
  for (int r = threadIdx.x; r < 2048; r += 256) rl4[r] = ((const float4*)r2)[r];
  __syncthreads();
  float acc[8];
  const float bv = d3b[j];
#pragma unroll
  for (int b = 0; b < 8; ++b) acc[b] = bv;
  const float4* wr = (const float4*)d3w + (long)j * 256;
  for (int k4 = 0; k4 < 256; ++k4) {
    const float4 w = wr[k4];
#pragma unroll
    for (int b = 0; b < 8; ++b) {
      const int o = b * 1024 + k4 * 4;
      acc[b] += w.x * rl[o] + w.y * rl[o + 1] + w.z * rl[o + 2] + w.w * rl[o + 3];
    }
  }
#pragma unroll
  for (int b = 0; b < 8; ++b)
    out[400 + b * 12288 + j] = 1.f / (1.f + __expf(-acc[b]));
}

extern "C" void kernel_launch(void* const* d_in, const int* in_sizes, int n_in,
                              void* d_out, int out_size, void* d_ws, size_t ws_size,
                              hipStream_t stream) {
  const float* x   = (const float*)d_in[0];
  const float* c1w = (const float*)d_in[1];
  const float* c1b = (const float*)d_in[2];
  const float* pw  = (const float*)d_in[3];
  const float* pb  = (const float*)d_in[4];
  const float* W   = (const float*)d_in[5];
  const float* d1w = (const float*)d_in[6];
  const float* d1b = (const float*)d_in[7];
  const float* d2w = (const float*)d_in[8];
  const float* d2b = (const float*)d_in[9];
  const float* d3w = (const float*)d_in[10];
  const float* d3b = (const float*)d_in[11];
  float* out = (float*)d_out;

  char* wsb = (char*)d_ws;
  size_t off = 0;
  auto alloc = [&](size_t bytes) -> char* {
    char* p = wsb + off;
    off += (bytes + 255) & ~(size_t)255;
    return p;
  };
  unsigned short* h_bf   = (unsigned short*)alloc(12845056);  // bf16 h (NCHW)
  unsigned short* wbf    = (unsigned short*)alloc(10616832);  // bf16 tiled prim_w
  unsigned*       offt   = (unsigned*)alloc(82944);
  // bigA aliases: C_part (8 partials, 37.7 MB) -> S1 (14.7 MB) -> S_part23 (29.5 MB)
  char*           bigA   = alloc(37748736);
  float*          C_part = (float*)bigA;
  float*          S1     = (float*)bigA;
  float*          S_part = (float*)bigA;
  float*          u      = (float*)alloc(4718592);
  float*          vsum   = (float*)alloc(25600);
  float*          v3     = (float*)alloc(25600);
  float*          selv   = (float*)alloc(512);
  int*            idxs   = (int*)alloc(64);
  float*          r1     = (float*)alloc(16384);
  float*          r2     = (float*)alloc(32768);
  const size_t off_base = off;
#if HAVE_FP8
  uint4*          uhat   = (uint4*)alloc(117964800);   // fp8 u_hat [n][i][b*16+d]
#else
  uint4*          uhat   = (uint4*)alloc(235929600);   // f16 u_hat
#endif
  const bool uhat_route = (off <= ws_size);
  if (off_base > ws_size) return;

  offtab_k<<<81, 256, 0, stream>>>(offt);
  wconv_k<<<2592, 256, 0, stream>>>(pw, wbf);
  conv1_k<<<2048, 256, 0, stream>>>(x, c1w, c1b, h_bf);
  prim_gemm<<<dim3(72, 8), 512, 0, stream>>>(h_bf, (const uint4*)wbf, offt, C_part);
  combine_k<<<576, 256, 0, stream>>>(C_part, pb, u);
  hipMemsetAsync(vsum, 0, 25600, stream);
  if (uhat_route) {
    route1_fused<<<28800, 512, 0, stream>>>(W, u, uhat, S1);
    route_reduce1<<<400, 256, 0, stream>>>(S1, vsum);
    for (int pass = 2; pass <= 3; ++pass) {
      route_uhat<<<1152, 256, 0, stream>>>((const uint4*)uhat, vsum, S_part);
      route_reduce<<<400, 256, 0, stream>>>(S_part, vsum, v3, pass, 1152);
    }
  } else {
    for (int pass = 1; pass <= 3; ++pass) {
      route_pass_f32<<<576, 512, 0, stream>>>(W, u, vsum, S_part);
      route_reduce<<<400, 256, 0, stream>>>(S_part, vsum, v3, pass, 576);
    }
  }
  head_k<<<1, 512, 0, stream>>>(v3, out, selv, idxs);
  d1_k<<<8, 512, 0, stream>>>(selv, idxs, d1w, d1b, r1);
  d2_k<<<dim3(4, 8), 256, 0, stream>>>(r1, d2w, d2b, r2);
  d3_k<<<48, 256, 0, stream>>>(r2, d3w, d3b, out);
}

// Round 20
// 605.914 us; speedup vs baseline: 1.0113x; 1.0113x over previous
//
#include <hip/hip_runtime.h>

typedef short short8 __attribute__((ext_vector_type(8)));
typedef float f32x4 __attribute__((ext_vector_type(4)));
typedef float f32x2 __attribute__((ext_vector_type(2)));
typedef _Float16 h2 __attribute__((ext_vector_type(2)));

#if __has_builtin(__builtin_amdgcn_cvt_pk_fp8_f32) && __has_builtin(__builtin_amdgcn_cvt_pk_f32_fp8)
#define HAVE_FP8 1
#else
#define HAVE_FP8 0
#endif

__device__ __forceinline__ unsigned short f2bf(float f) {
  union { float f; unsigned u; } a; a.f = f;
  unsigned r = a.u + 0x7fffu + ((a.u >> 16) & 1u);
  return (unsigned short)(r >> 16);
}

__device__ __forceinline__ h2 u2h2(unsigned w) {
  union { unsigned u; h2 h; } q; q.u = w; return q.h;
}

__device__ __forceinline__ unsigned short f2h(float f) {
  union { _Float16 h; unsigned short s; } q; q.h = (_Float16)f; return q.s;
}

// ---------------- tap offset table: off[k] = ci*3136 + ky*56 + kx ----------------
__global__ void offtab_k(unsigned* __restrict__ off_tab) {
  const int k = blockIdx.x * 256 + threadIdx.x;  // 81*256 = 20736 exact
  const int ci = k / 81, rr = k % 81;
  const int ky = rr / 9, kx = rr % 9;
  off_tab[k] = (unsigned)(ci * 3136 + ky * 56 + kx);
}

// ---------------- prim_w fp32 -> bf16 tiled [kb][co][8] ----------------
__global__ __launch_bounds__(256) void wconv_k(const float* __restrict__ pw,
                                               unsigned short* __restrict__ wbf) {
  const int kb = blockIdx.x, co = threadIdx.x;  // 2592 blocks
  const float4* src = (const float4*)(pw + (long)co * 20736 + kb * 8);
  const float4 a = src[0], b = src[1];
  union { unsigned short s[8]; short8 v; } o;
  o.s[0] = f2bf(a.x); o.s[1] = f2bf(a.y); o.s[2] = f2bf(a.z); o.s[3] = f2bf(a.w);
  o.s[4] = f2bf(b.x); o.s[5] = f2bf(b.y); o.s[6] = f2bf(b.z); o.s[7] = f2bf(b.w);
  *reinterpret_cast<short8*>(&wbf[((long)kb * 256 + co) * 8]) = o.v;
}

// ---------------- conv1: [8,3,64,64] -> bf16 h [8,256,56,56], relu ----------------
__global__ __launch_bounds__(256) void conv1_k(const float* __restrict__ x,
                                               const float* __restrict__ w,
                                               const float* __restrict__ bias,
                                               unsigned short* __restrict__ h_bf) {
  __shared__ float xl[12288];
  __shared__ float wl[244];
  const int blk = blockIdx.x;          // 2048 = 8b * 256co
  const int b = blk >> 8, co = blk & 255;
  const int t = threadIdx.x;
  const float4* xb = (const float4*)(x + b * 12288);
  float4* xl4 = (float4*)xl;
  for (int r = t; r < 3072; r += 256) xl4[r] = xb[r];
  for (int r = t; r < 243; r += 256) wl[r] = w[co * 243 + r];
  __syncthreads();
  if (t >= 224) return;
  const int ox = t % 56, oy0 = (t / 56) * 14;
  float acc[14];
#pragma unroll
  for (int j = 0; j < 14; ++j) acc[j] = 0.f;
  for (int ci = 0; ci < 3; ++ci)
    for (int kx = 0; kx < 9; ++kx) {
      const int base = ci * 4096 + oy0 * 64 + ox + kx;
      float win[22];
#pragma unroll
      for (int q = 0; q < 22; ++q) win[q] = xl[base + q * 64];
#pragma unroll
      for (int ky = 0; ky < 9; ++ky) {
        const float wv = wl[ci * 81 + ky * 9 + kx];
#pragma unroll
        for (int j = 0; j < 14; ++j) acc[j] = fmaf(wv, win[j + ky], acc[j]);
      }
    }
  const float bv = bias[co];
  unsigned short* hp = h_bf + (((long)b * 256 + co) * 56 + oy0) * 56 + ox;
#pragma unroll
  for (int j = 0; j < 14; ++j) {
    float v = acc[j] + bv;
    v = v > 0.f ? v : 0.f;
    hp[j * 56] = f2bf(v);
  }
}

// ---------------- prim conv implicit GEMM v11: BK=32, DOUBLE-BUFFERED LDS ----------------
// C[m=4608][co=256], K=20736. grid (72 mtile, 4 ksplit), 512 thr = 8 waves (2M x 4N).
// ONE barrier per k-step; load->use distance = 2 iterations. Best proven config (607 us).
__global__ __launch_bounds__(512) void prim_gemm(const unsigned short* __restrict__ h_bf,
                                                 const uint4* __restrict__ wbf4,
                                                 const unsigned* __restrict__ off_tab,
                                                 float* __restrict__ C_part) {
  __shared__ uint4 A4[2][256];    // [buf][c:4][row:64]
  __shared__ uint4 B4[2][1024];   // [buf][c:4][co:256]
  const int t = threadIdx.x;
  const int lane = t & 63, w = t >> 6;
  const int mt = blockIdx.x, kz = blockIdx.y;
  const int k0 = kz * 5184;  // 162 k-steps of 32
  const bool isA = (t < 256);
  const int ar = t & 63, ac = (t >> 6) & 3;
  const int m = mt * 64 + ar;
  const int b = m / 576, yx = m % 576;
  const int oy = yx / 24, ox = yx % 24;
  const long base_p = (long)b * 802816 + oy * 112 + ox * 2;
  const int bco = t & 255;
  const int wm = w >> 2, wn = w & 3;
  const int fr = lane & 15, fg = lane >> 4;
  f32x4 acc[2][4];
#pragma unroll
  for (int i2 = 0; i2 < 2; ++i2)
#pragma unroll
    for (int j = 0; j < 4; ++j)
#pragma unroll
      for (int e = 0; e < 4; ++e) acc[i2][j][e] = 0.f;

  union { unsigned short s[8]; uint4 v; } pa;
  uint4 pb0, pb1, pb2, pb3;
  auto loadA = [&](int kt) {
    const int kb = k0 + kt * 32 + ac * 8;
#pragma unroll
    for (int j = 0; j < 8; ++j) pa.s[j] = h_bf[base_p + off_tab[kb + j]];
  };
  auto loadB = [&](int kt) {
    const int kb0 = (k0 + kt * 32) >> 3;
    pb0 = wbf4[(kb0 + 0) * 256 + bco];
    pb1 = wbf4[(kb0 + 1) * 256 + bco];
    pb2 = wbf4[(kb0 + 2) * 256 + bco];
    pb3 = wbf4[(kb0 + 3) * 256 + bco];
  };
  // prologue: tile 0 -> buf0; prefetch tile 1 into regs
  if (isA) loadA(0); else loadB(0);
  if (isA) {
    A4[0][ac * 64 + ar] = pa.v;
  } else {
    B4[0][bco] = pb0;
    B4[0][256 + bco] = pb1;
    B4[0][512 + bco] = pb2;
    B4[0][768 + bco] = pb3;
  }
  if (isA) loadA(1); else loadB(1);
  __syncthreads();

  for (int kt = 0; kt < 162; ++kt) {
    const int cur = kt & 1, nxt = cur ^ 1;
    if (kt < 161) {  // stage tile kt+1 (in regs) into the other buffer
      if (isA) {
        A4[nxt][ac * 64 + ar] = pa.v;
      } else {
        B4[nxt][bco] = pb0;
        B4[nxt][256 + bco] = pb1;
        B4[nxt][512 + bco] = pb2;
        B4[nxt][768 + bco] = pb3;
      }
      if (kt < 160) { if (isA) loadA(kt + 2); else loadB(kt + 2); }
    }
    const short8* A8 = (const short8*)A4[cur];
    const short8* B8 = (const short8*)B4[cur];
    const short8 a0 = A8[fg * 64 + wm * 32 + fr];
    const short8 a1 = A8[fg * 64 + wm * 32 + 16 + fr];
    const short8 b0 = B8[fg * 256 + wn * 64 + fr];
    const short8 b1 = B8[fg * 256 + wn * 64 + 16 + fr];
    const short8 b2 = B8[fg * 256 + wn * 64 + 32 + fr];
    const short8 b3 = B8[fg * 256 + wn * 64 + 48 + fr];
    acc[0][0] = __builtin_amdgcn_mfma_f32_16x16x32_bf16(a0, b0, acc[0][0], 0, 0, 0);
    acc[0][1] = __builtin_amdgcn_mfma_f32_16x16x32_bf16(a0, b1, acc[0][1], 0, 0, 0);
    acc[0][2] = __builtin_amdgcn_mfma_f32_16x16x32_bf16(a0, b2, acc[0][2], 0, 0, 0);
    acc[0][3] = __builtin_amdgcn_mfma_f32_16x16x32_bf16(a0, b3, acc[0][3], 0, 0, 0);
    acc[1][0] = __builtin_amdgcn_mfma_f32_16x16x32_bf16(a1, b0, acc[1][0], 0, 0, 0);
    acc[1][1] = __builtin_amdgcn_mfma_f32_16x16x32_bf16(a1, b1, acc[1][1], 0, 0, 0);
    acc[1][2] = __builtin_amdgcn_mfma_f32_16x16x32_bf16(a1, b2, acc[1][2], 0, 0, 0);
    acc[1][3] = __builtin_amdgcn_mfma_f32_16x16x32_bf16(a1, b3, acc[1][3], 0, 0, 0);
    __syncthreads();
  }
#pragma unroll
  for (int i2 = 0; i2 < 2; ++i2)
#pragma unroll
    for (int j = 0; j < 4; ++j)
#pragma unroll
      for (int e = 0; e < 4; ++e) {
        const int row = mt * 64 + wm * 32 + i2 * 16 + fg * 4 + e;
        const int col = wn * 64 + j * 16 + fr;
        C_part[((long)kz * 4608 + row) * 256 + col] = acc[i2][j][e];
      }
}

// ------- combine 4 K-split partials + bias + squash -> u fp32 [8,18432,8] -------
__global__ __launch_bounds__(256) void combine_k(const float* __restrict__ C_part,
                                                 const float* __restrict__ prim_b,
                                                 float* __restrict__ u) {
  const int cap = blockIdx.x * 256 + threadIdx.x;
  const int b = cap / 18432, r = cap % 18432;
  const int g = r / 576, yx = r % 576;
  const long m = (long)b * 576 + yx;
  float pv[8];
#pragma unroll
  for (int e = 0; e < 8; ++e) pv[e] = prim_b[g * 8 + e];
#pragma unroll
  for (int kz = 0; kz < 4; ++kz) {
    const float4* cp = (const float4*)(C_part + ((long)kz * 4608 + m) * 256 + g * 8);
    const float4 f0 = cp[0], f1 = cp[1];
    pv[0] += f0.x; pv[1] += f0.y; pv[2] += f0.z; pv[3] += f0.w;
    pv[4] += f1.x; pv[5] += f1.y; pv[6] += f1.z; pv[7] += f1.w;
  }
  float sn = 0.f;
#pragma unroll
  for (int e = 0; e < 8; ++e) sn += pv[e] * pv[e];
  const float f = sn / (1.f + sn) / (sqrtf(sn) + 1e-8f);
  float4 o0, o1;
  o0.x = pv[0] * f; o0.y = pv[1] * f; o0.z = pv[2] * f; o0.w = pv[3] * f;
  o1.x = pv[4] * f; o1.y = pv[5] * f; o1.z = pv[6] * f; o1.w = pv[7] * f;
  float4* up = (float4*)(u + (long)cap * 8);
  up[0] = o0; up[1] = o1;
}

// ---------------- fused pass1 + u_hat materialization ----------------
__global__ __launch_bounds__(512) void route1_fused(const float* __restrict__ W,
                                                    const float* __restrict__ u,
                                                    uint4* __restrict__ uhat4,
                                                    float* __restrict__ S1) {
  __shared__ float4 u_l[8][64];
  __shared__ float red[8][128];
#if HAVE_FP8
  __shared__ unsigned char ubuf[32][128];   // fp8 staging, 4 KB
#endif
  const int blk = blockIdx.x;
  const int t = threadIdx.x;
  const int n = blk / 576;
  const int i0 = (blk % 576) * 32;
  const long unit = (long)blk * 512 + t;
  {
    const int b = t >> 6, f = t & 63;
    u_l[b][f] = ((const float4*)(u + ((long)b * 18432 + i0) * 8))[f];
  }
  const float4* ws = (const float4*)(W + unit * 8);
  const float4 wa = ws[0], wb = ws[1];
  __syncthreads();
  const int il = t >> 4, d = t & 15;
  const int w = t >> 6, lane = t & 63;
  float uh[8];
#pragma unroll
  for (int b = 0; b < 8; ++b) {
    const float4 p0 = u_l[b][il * 2], p1 = u_l[b][il * 2 + 1];
    uh[b] = wa.x * p0.x + wa.y * p0.y + wa.z * p0.z + wa.w * p0.w +
            wb.x * p1.x + wb.y * p1.y + wb.z * p1.z + wb.w * p1.w;
  }
#if HAVE_FP8
#pragma unroll
  for (int b = 0; b < 8; ++b) {
    const int v8 = __builtin_amdgcn_cvt_pk_fp8_f32(uh[b] * 256.f, 0.f, 0, false);
    ubuf[il][b * 16 + d] = (unsigned char)(v8 & 0xff);
  }
#else
  unsigned short* up = (unsigned short*)uhat4 + ((long)n * 18432 + i0 + il) * 128 + d;
#pragma unroll
  for (int b = 0; b < 8; ++b) up[b * 16] = f2h(uh[b]);
#endif
#pragma unroll
  for (int b = 0; b < 8; ++b) {
    float v = uh[b];
    v += __shfl_xor(v, 16);   // reduce over i_local bits (lane bits 4,5)
    v += __shfl_xor(v, 32);
    if (lane < 16) red[w][b * 16 + lane] = v;
  }
  __syncthreads();
#if HAVE_FP8
  if (t < 256) {   // 32 rows x 128B = 256 uint4, coalesced
    const uint4* ub4 = (const uint4*)ubuf;
    uhat4[((long)n * 18432 + i0) * 8 + t] = ub4[t];
  }
#endif
  if (t < 128) {
    float s = 0.f;
#pragma unroll
    for (int w2 = 0; w2 < 8; ++w2) s += red[w2][t];
    S1[(long)blk * 128 + t] = s;
  }
}

__global__ __launch_bounds__(256) void route_reduce1(const float* __restrict__ S1,
                                                     float* __restrict__ vsum) {
  __shared__ float lds[256];
  const int bn = blockIdx.x;
  const int b = bn / 50, n = bn % 50;
  const int t = threadIdx.x;
  const int kk = t >> 4, dd = t & 15;
  float s = 0.f;
  const float* p = S1 + (long)n * 576 * 128 + b * 16 + dd;
  for (int j = kk; j < 576; j += 16) s += p[(long)j * 128];
  lds[t] = s;
  __syncthreads();
  for (int off = 128; off >= 16; off >>= 1) {
    if (t < off) lds[t] += lds[t + off];
    __syncthreads();
  }
  if (t < 16) {
    const float S = lds[t] * 0.02f;
    float sq = S * S;
    sq += __shfl_xor(sq, 1);
    sq += __shfl_xor(sq, 2);
    sq += __shfl_xor(sq, 4);
    sq += __shfl_xor(sq, 8);
    const float f = sq / (1.f + sq) / (sqrtf(sq) + 1e-8f);
    vsum[bn * 16 + t] += S * f;
  }
}

// ---------------- routing passes 2/3 from materialized u_hat ----------------
__global__ __launch_bounds__(256) void route_uhat(const uint4* __restrict__ uh4,
                                                  const float* __restrict__ vsum,
                                                  float* __restrict__ S_part) {
  const int t = threadIdx.x;
  const int w = t >> 6, lane = t & 63;
  const int b0 = 2 * w;
  const bool vn = lane < 50;
  const int nr = vn ? lane : 49;
  const int bi = blockIdx.x;
  const int i_base = bi * 16;

  float vs0[16], vs1[16], Sa0[16], Sa1[16];
#pragma unroll
  for (int d = 0; d < 16; ++d) {
    vs0[d] = vsum[(b0 * 50 + nr) * 16 + d];
    vs1[d] = vsum[((b0 + 1) * 50 + nr) * 16 + d];
    Sa0[d] = 0.f;
    Sa1[d] = 0.f;
  }

#if HAVE_FP8
  const float INV = 1.f / 256.f;
  auto base4 = [&](int i) -> long { return ((long)nr * 18432 + i) * 8 + b0; };
  uint4 c0, c1;
  { const long p = base4(i_base); c0 = uh4[p]; c1 = uh4[p + 1]; }
  for (int ii = 0; ii < 16; ++ii) {
    uint4 n0, n1;
    if (ii < 15) { const long p = base4(i_base + ii + 1); n0 = uh4[p]; n1 = uh4[p + 1]; }
    float uh0[16], uh1[16];
    {
      const unsigned* q0 = (const unsigned*)&c0;
      const unsigned* q1 = (const unsigned*)&c1;
#pragma unroll
      for (int qw = 0; qw < 4; ++qw) {
        const f32x2 lo0 = __builtin_amdgcn_cvt_pk_f32_fp8(q0[qw], false);
        const f32x2 hi0 = __builtin_amdgcn_cvt_pk_f32_fp8(q0[qw], true);
        uh0[qw * 4 + 0] = lo0[0]; uh0[qw * 4 + 1] = lo0[1];
        uh0[qw * 4 + 2] = hi0[0]; uh0[qw * 4 + 3] = hi0[1];
        const f32x2 lo1 = __builtin_amdgcn_cvt_pk_f32_fp8(q1[qw], false);
        const f32x2 hi1 = __builtin_amdgcn_cvt_pk_f32_fp8(q1[qw], true);
        uh1[qw * 4 + 0] = lo1[0]; uh1[qw * 4 + 1] = lo1[1];
        uh1[qw * 4 + 2] = hi1[0]; uh1[qw * 4 + 3] = hi1[1];
      }
    }
#else
  const float INV = 1.f;
  auto base4 = [&](int i) -> long { return ((long)nr * 18432 + i) * 16 + b0 * 2; };
  uint4 c0, c1, c2, c3;
  { const long p = base4(i_base); c0 = uh4[p]; c1 = uh4[p + 1]; c2 = uh4[p + 2]; c3 = uh4[p + 3]; }
  for (int ii = 0; ii < 16; ++ii) {
    uint4 n0, n1, n2, n3;
    if (ii < 15) {
      const long p = base4(i_base + ii + 1);
      n0 = uh4[p]; n1 = uh4[p + 1]; n2 = uh4[p + 2]; n3 = uh4[p + 3];
    }
    float uh0[16], uh1[16];
    {
      const unsigned* w0 = (const unsigned*)&c0;
      const unsigned* w1 = (const unsigned*)&c1;
      const unsigned* w2 = (const unsigned*)&c2;
      const unsigned* w3 = (const unsigned*)&c3;
#pragma unroll
      for (int q = 0; q < 4; ++q) {
        h2 hh = u2h2(w0[q]); uh0[q * 2] = (float)hh[0]; uh0[q * 2 + 1] = (float)hh[1];
        hh = u2h2(w1[q]); uh0[8 + q * 2] = (float)hh[0]; uh0[8 + q * 2 + 1] = (float)hh[1];
        hh = u2h2(w2[q]); uh1[q * 2] = (float)hh[0]; uh1[q * 2 + 1] = (float)hh[1];
        hh = u2h2(w3[q]); uh1[8 + q * 2] = (float)hh[0]; uh1[8 + q * 2 + 1] = (float)hh[1];
      }
    }
#endif
    float lg0 = 0.f, lg1 = 0.f;
#pragma unroll
    for (int d = 0; d < 16; ++d) {
      lg0 = fmaf(uh0[d], vs0[d], lg0);
      lg1 = fmaf(uh1[d], vs1[d], lg1);
    }
    float p0 = vn ? __expf(lg0 * INV) : 0.f;
    float p1 = vn ? __expf(lg1 * INV) : 0.f;
    float sm0 = p0, sm1 = p1;
    sm0 += __shfl_xor(sm0, 1);
    sm1 += __shfl_xor(sm1, 1);
    sm0 += __shfl_xor(sm0, 2);
    sm1 += __shfl_xor(sm1, 2);
    sm0 += __shfl_xor(sm0, 4);
    sm1 += __shfl_xor(sm1, 4);
    sm0 += __shfl_xor(sm0, 8);
    sm1 += __shfl_xor(sm1, 8);
    sm0 += __shfl_xor(sm0, 16);
    sm1 += __shfl_xor(sm1, 16);
    sm0 += __shfl_xor(sm0, 32);
    sm1 += __shfl_xor(sm1, 32);
    const float sc0 = p0 / sm0;
    const float sc1 = p1 / sm1;
#pragma unroll
    for (int d = 0; d < 16; ++d) {
      Sa0[d] = fmaf(sc0, uh0[d], Sa0[d]);
      Sa1[d] = fmaf(sc1, uh1[d], Sa1[d]);
    }
#if HAVE_FP8
    c0 = n0; c1 = n1;
#else
    c0 = n0; c1 = n1; c2 = n2; c3 = n3;
#endif
  }
  if (vn) {
    float* Sp0 = S_part + (long)bi * 6400 + b0 * 800 + lane * 16;
    float* Sp1 = Sp0 + 800;
#pragma unroll
    for (int d = 0; d < 16; ++d) {
      Sp0[d] = Sa0[d] * INV;
      Sp1[d] = Sa1[d] * INV;
    }
  }
}

// ---------------- routing pass (fp32 fallback, proven; 576 blocks) ----------------
__global__ __launch_bounds__(512, 4) void route_pass_f32(const float* __restrict__ W,
                                                         const float* __restrict__ u,
                                                         const float* __restrict__ vsum,
                                                         float* __restrict__ S_part) {
  const int t = threadIdx.x;
  const int b = t >> 6;
  const int lane = t & 63;
  const int d = lane & 15, nq = lane >> 4;
  const int qmax = (nq == 3) ? 11 : 13;
  int nn[13];
  float vs[13], Sa[13], uh[13], lg[13];
#pragma unroll
  for (int q = 0; q < 13; ++q) {
    const int n = nq * 13 + q;
    const bool valid = n < 50;
    nn[q] = valid ? n : 49;
    vs[q] = valid ? vsum[(b * 50 + n) * 16 + d] : 0.f;
    Sa[q] = 0.f;
  }
  const int bi = blockIdx.x;
  for (int ii = 0; ii < 32; ++ii) {
    const int i = bi * 32 + ii;
    const float4* up = (const float4*)(u + ((long)b * 18432 + i) * 8);
    const float4 u0 = up[0], u1 = up[1];
    const float* Wi = W + (long)i * 128 + d * 8;
#pragma unroll
    for (int q = 0; q < 13; ++q) {
      const float4* wp = (const float4*)(Wi + (long)nn[q] * 2359296);
      const float4 w0 = wp[0], w1 = wp[1];
      const float s = w0.x * u0.x + w0.y * u0.y + w0.z * u0.z + w0.w * u0.w +
                      w1.x * u1.x + w1.y * u1.y + w1.z * u1.z + w1.w * u1.w;
      uh[q] = s;
      float v = s * vs[q];
      v += __shfl_xor(v, 1);
      v += __shfl_xor(v, 2);
      v += __shfl_xor(v, 4);
      v += __shfl_xor(v, 8);
      lg[q] = (q < qmax) ? v : -1e30f;
    }
    float mx = lg[0];
#pragma unroll
    for (int q = 1; q < 13; ++q) mx = fmaxf(mx, lg[q]);
    mx = fmaxf(mx, __shfl_xor(mx, 16));
    mx = fmaxf(mx, __shfl_xor(mx, 32));
    float sm = 0.f;
#pragma unroll
    for (int q = 0; q < 13; ++q) {
      const float e = __expf(lg[q] - mx);
      lg[q] = e;
      sm += e;
    }
    sm += __shfl_xor(sm, 16);
    sm += __shfl_xor(sm, 32);
    const float inv = 1.f / sm;
#pragma unroll
    for (int q = 0; q < 13; ++q) Sa[q] = fmaf(lg[q] * inv, uh[q], Sa[q]);
  }
  float* Sp = S_part + ((long)bi * 8 + b) * 800;
#pragma unroll
  for (int q = 0; q < 13; ++q)
    if (q < qmax) Sp[(nq * 13 + q) * 16 + d] = Sa[q];
}

// ---------------- reduce nparts partials -> v = squash(S); vsum += v or v3 = v ------
__global__ __launch_bounds__(256) void route_reduce(const float* __restrict__ S_part,
                                                    float* __restrict__ vsum,
                                                    float* __restrict__ v3,
                                                    const int pass, const int nparts) {
  __shared__ float lds[256];
  const int bn = blockIdx.x;
  const int b = bn / 50, n = bn % 50;
  const int t = threadIdx.x;
  const int kk = t >> 4, dd = t & 15;
  float s = 0.f;
  const float* p = S_part + (long)b * 800 + n * 16 + dd;
  for (int j = kk; j < nparts; j += 16) s += p[(long)j * 6400];
  lds[t] = s;
  __syncthreads();
  for (int off = 128; off >= 16; off >>= 1) {
    if (t < off) lds[t] += lds[t + off];
    __syncthreads();
  }
  if (t < 16) {
    const float S = lds[t];
    float sq = S * S;
    sq += __shfl_xor(sq, 1);
    sq += __shfl_xor(sq, 2);
    sq += __shfl_xor(sq, 4);
    sq += __shfl_xor(sq, 8);
    const float f = sq / (1.f + sq) / (sqrtf(sq) + 1e-8f);
    const float v = S * f;
    const int o = bn * 16 + t;
    if (pass < 3) vsum[o] += v;
    else v3[o] = v;
  }
}

// ---------------- preds, argmax, select masked capsule ----------------
__global__ __launch_bounds__(512) void head_k(const float* __restrict__ v3,
                                              float* __restrict__ out,
                                              float* __restrict__ selv,
                                              int* __restrict__ idxs) {
  __shared__ float pl[400];
  const int t = threadIdx.x;
  if (t < 400) {
    const float4* vp = (const float4*)(v3 + t * 16);
    const float4 a = vp[0], b = vp[1], c = vp[2], d = vp[3];
    const float s = a.x * a.x + a.y * a.y + a.z * a.z + a.w * a.w +
                    b.x * b.x + b.y * b.y + b.z * b.z + b.w * b.w +
                    c.x * c.x + c.y * c.y + c.z * c.z + c.w * c.w +
                    d.x * d.x + d.y * d.y + d.z * d.z + d.w * d.w;
    const float p = sqrtf(s);
    out[t] = p;
    pl[t] = p;
  }
  __syncthreads();
  if (t < 8) {
    float best = -1e30f;
    int bi = 0;
    for (int n = 0; n < 50; ++n) {
      const float p = pl[t * 50 + n];
      if (p > best) { best = p; bi = n; }
    }
    idxs[t] = bi;
    for (int k = 0; k < 16; ++k) selv[t * 16 + k] = v3[(t * 50 + bi) * 16 + k];
  }
}

// ---------------- decoder ----------------
__global__ __launch_bounds__(512) void d1_k(const float* __restrict__ selv,
                                            const int* __restrict__ idxs,
                                            const float* __restrict__ d1w,
                                            const float* __restrict__ d1b,
                                            float* __restrict__ r1) {
  const int b = blockIdx.x, j = threadIdx.x;
  const int idx = idxs[b];
  const float* wr = d1w + j * 800 + idx * 16;
  float acc = d1b[j];
#pragma unroll
  for (int k = 0; k < 16; ++k) acc = fmaf(selv[b * 16 + k], wr[k], acc);
  r1[b * 512 + j] = acc > 0.f ? acc : 0.f;
}

__global__ __launch_bounds__(256) void d2_k(const float* __restrict__ r1,
                                            const float* __restrict__ d2w,
                                            const float* __restrict__ d2b,
                                            float* __restrict__ r2) {
  __shared__ float rl[512];
  const int b = blockIdx.y;
  const int j = blockIdx.x * 256 + threadIdx.x;
  for (int r = threadIdx.x; r < 512; r += 256) rl[r] = r1[b * 512 + r];
  __syncthreads();
  const float4* wr = (const float4*)(d2w + (long)j * 512);
  float acc = d2b[j];
  for (int k4 = 0; k4 < 128; ++k4) {
    const float4 w = wr[k4];
    acc += w.x * rl[k4 * 4] + w.y * rl[k4 * 4 + 1] + w.z * rl[k4 * 4 + 2] + w.w * rl[k4 * 4 + 3];
  }
  r2[b * 1024 + j] = acc > 0.f ? acc : 0.f;
}

__global__ __launch_bounds__(256) void d3_k(const float* __restrict__ r2,
                                            const float* __restrict__ d3w,
                                            const float* __restrict__ d3b,
                                            float* __restrict__ out) {
  __shared__ float rl[8192];
  const int j = blockIdx.x * 256 + threadIdx.x;
  float4* rl4 = (float4*)rl;
  for (int r = threadIdx.x; r < 2048; r += 256) rl4[r] = ((const float4*)r2)[r];
  __syncthreads();
  float acc[8];
  const float bv = d3b[j];
#pragma unroll
  for (int b = 0; b < 8; ++b) acc[b] = bv;
  const float4* wr = (const float4*)d3w + (long)j * 256;
  for (int k4 = 0; k4 < 256; ++k4) {
    const float4 w = wr[k4];
#pragma unroll
    for (int b = 0; b < 8; ++b) {
      const int o = b * 1024 + k4 * 4;
      acc[b] += w.x * rl[o] + w.y * rl[o + 1] + w.z * rl[o + 2] + w.w * rl[o + 3];
    }
  }
#pragma unroll
  for (int b = 0; b < 8; ++b)
    out[400 + b * 12288 + j] = 1.f / (1.f + __expf(-acc[b]));
}

extern "C" void kernel_launch(void* const* d_in, const int* in_sizes, int n_in,
                              void* d_out, int out_size, void* d_ws, size_t ws_size,
                              hipStream_t stream) {
  const float* x   = (const float*)d_in[0];
  const float* c1w = (const float*)d_in[1];
  const float* c1b = (const float*)d_in[2];
  const float* pw  = (const float*)d_in[3];
  const float* pb  = (const float*)d_in[4];
  const float* W   = (const float*)d_in[5];
  const float* d1w = (const float*)d_in[6];
  const float* d1b = (const float*)d_in[7];
  const float* d2w = (const float*)d_in[8];
  const float* d2b = (const float*)d_in[9];
  const float* d3w = (const float*)d_in[10];
  const float* d3b = (const float*)d_in[11];
  float* out = (float*)d_out;

  char* wsb = (char*)d_ws;
  size_t off = 0;
  auto alloc = [&](size_t bytes) -> char* {
    char* p = wsb + off;
    off += (bytes + 255) & ~(size_t)255;
    return p;
  };
  unsigned short* h_bf   = (unsigned short*)alloc(12845056);  // bf16 h (NCHW)
  unsigned short* wbf    = (unsigned short*)alloc(10616832);  // bf16 tiled prim_w
  unsigned*       offt   = (unsigned*)alloc(82944);
  // bigA aliases: C_part (18.9 MB) -> S1 (14.7 MB) -> S_part23 (29.5 MB)
  char*           bigA   = alloc(29491200);
  float*          C_part = (float*)bigA;
  float*          S1     = (float*)bigA;
  float*          S_part = (float*)bigA;
  float*          u      = (float*)alloc(4718592);
  float*          vsum   = (float*)alloc(25600);
  float*          v3     = (float*)alloc(25600);
  float*          selv   = (float*)alloc(512);
  int*            idxs   = (int*)alloc(64);
  float*          r1     = (float*)alloc(16384);
  float*          r2     = (float*)alloc(32768);
  const size_t off_base = off;
#if HAVE_FP8
  uint4*          uhat   = (uint4*)alloc(117964800);   // fp8 u_hat [n][i][b*16+d]
#else
  uint4*          uhat   = (uint4*)alloc(235929600);   // f16 u_hat
#endif
  const bool uhat_route = (off <= ws_size);
  if (off_base > ws_size) return;

  offtab_k<<<81, 256, 0, stream>>>(offt);
  wconv_k<<<2592, 256, 0, stream>>>(pw, wbf);
  conv1_k<<<2048, 256, 0, stream>>>(x, c1w, c1b, h_bf);
  prim_gemm<<<dim3(72, 4), 512, 0, stream>>>(h_bf, (const uint4*)wbf, offt, C_part);
  combine_k<<<576, 256, 0, stream>>>(C_part, pb, u);
  hipMemsetAsync(vsum, 0, 25600, stream);
  if (uhat_route) {
    route1_fused<<<28800, 512, 0, stream>>>(W, u, uhat, S1);
    route_reduce1<<<400, 256, 0, stream>>>(S1, vsum);
    for (int pass = 2; pass <= 3; ++pass) {
      route_uhat<<<1152, 256, 0, stream>>>((const uint4*)uhat, vsum, S_part);
      route_reduce<<<400, 256, 0, stream>>>(S_part, vsum, v3, pass, 1152);
    }
  } else {
    for (int pass = 1; pass <= 3; ++pass) {
      route_pass_f32<<<576, 512, 0, stream>>>(W, u, vsum, S_part);
      route_reduce<<<400, 256, 0, stream>>>(S_part, vsum, v3, pass, 576);
    }
  }
  head_k<<<1, 512, 0, stream>>>(v3, out, selv, idxs);
  d1_k<<<8, 512, 0, stream>>>(selv, idxs, d1w, d1b, r1);
  d2_k<<<dim3(4, 8), 256, 0, stream>>>(r1, d2w, d2b, r2);
  d3_k<<<48, 256, 0, stream>>>(r2, d3w, d3b, out);
}